// Round 18
// baseline (164.163 us; speedup 1.0000x reference)
//
#include <hip/hip_runtime.h>
#include <hip/hip_bf16.h>
#include <math.h>

#define TB 8
#define TT 2048
#define TD 64
#define TK 5
#define TPAD 12
#define EPSBN 1e-5f
#define UMAX 4096

#define ROWS 64          // mm1: output rows per block (4 waves x 16)
#define BAND 66          // ROWS + 2 halo
#define LROWS 198        // 3 bands

// mm2f geometry
#define ROWS2 16
#define BAND2 18
#define LROWS2 54
#define SH8   432
#define BUFB  6912

#define ACG 17           // strip groups (4 strips/block -> 68 >= 65 needed)

typedef __attribute__((ext_vector_type(8))) short short8;
typedef __attribute__((ext_vector_type(4))) float f32x4;

// ws layout (float offsets)
#define OFF_S     0
#define OFF_SBF   1048576
#define OFF_R     1572864
#define OFF_IDX   1581056
#define OFF_W     1581096
#define OFF_WT1   1581136
#define OFF_WT2   1599568
#define OFF_H1    1618000
#define OFF_CAND  6860880
// end 6860944 floats = 27.4 MB

// ---------------- fused: trend/seasonal (sliding window) + weight repack + r zero ----------------
__global__ __launch_bounds__(256) void k_trend(const float* __restrict__ x,
                                               float* __restrict__ out, float* __restrict__ s,
                                               __hip_bfloat16* __restrict__ sbf,
                                               const float* __restrict__ w1, const float* __restrict__ w2,
                                               __hip_bfloat16* __restrict__ wt1, __hip_bfloat16* __restrict__ wt2,
                                               float* __restrict__ r)
{
    if (blockIdx.x >= 256) {
        int d = (blockIdx.x - 256) * 256 + threadIdx.x;
        if (d < TB * 1024) r[d] = 0.f;             // zero autocorr accumulator (replay-safe)
        if (d < 36864) {
            int j = d & 7, l = (d >> 3) & 63, nt = (d >> 9) & 3, kb = d >> 11;
            int tap = kb >> 1, half = kb & 1;
            int co = nt * 16 + (l & 15);
            int ci = half * 32 + (l >> 4) * 8 + j;
            int src = (co * 64 + ci) * 9 + tap;
            wt1[d] = __float2bfloat16(w1[src]);
            wt2[d] = __float2bfloat16(w2[src]);
        }
        return;
    }
    int gid = blockIdx.x * 256 + threadIdx.x;      // 65536 threads
    int c = gid & 63;
    int tblk = (gid >> 6) & 127;
    int b = gid >> 13;
    int t0 = tblk * 16;
    const float* base = x + (size_t)b * TT * TD + c;
    float sum = 0.f;
    for (int tt = t0 - TPAD; tt <= t0 + TPAD; ++tt)
        if (tt >= 0 && tt < TT) sum += base[(size_t)tt * TD];
    size_t o = (size_t)b * TT * TD + (size_t)t0 * TD + c;
    #pragma unroll
    for (int i = 0; i < 16; ++i) {
        int t = t0 + i;
        int lo = t - TPAD; if (lo < 0) lo = 0;
        int hi = t + TPAD; if (hi > TT - 1) hi = TT - 1;
        float tr = sum / (float)(hi - lo + 1);
        float xv = base[(size_t)t * TD];
        out[o] = xv + tr;
        float sv = xv - tr;
        s[o] = sv;
        sbf[o] = __float2bfloat16(sv);
        int addt = t + TPAD + 1, subt = t - TPAD;
        if (addt < TT) sum += base[(size_t)addt * TD];
        if (subt >= 0) sum -= base[(size_t)subt * TD];
        o += TD;
    }
}

// ---------------- autocorr via MFMA strips (bf16 in, f32 acc) ----------------
// r[l] = (1/64) sum_t sum_c s[t,c] s[(t+l)%T,c].  Strip D = tile-offset: for wave strip
// Delta, acc[m][n] += sum_c s[16ti+m,c]*s[16((ti+Delta)%128)+n,c] accumulated over ti.
// lag = 16*Delta + n - m (only 1..1024 kept).  Grid 544 = 68 slots x 8 b (b=id&7 -> XCD).
// Block: 4 waves = strips d0..d0+3, 32 ti-steps; LDS tile rings, XOR-swizzled.
__global__ __launch_bounds__(256) void k_ac_mfma(const short* __restrict__ sbf16, float* __restrict__ r)
{
    int id = blockIdx.x;
    int b = id & 7;
    int slot = id >> 3;                  // 0..67
    int g = slot % ACG;                  // 0..16
    int qq = slot / ACG;                 // 0..3
    int d0 = g * 4;
    int t0 = qq * 32;
    const short* sb = sbf16 + (size_t)b * TT * TD;

    __shared__ short Atile[2][1024];
    __shared__ short Btile[6][1024];
    __shared__ float scr[4][16 * 17];

    int tid = threadIdx.x;
    // prologue: stage A[t0], B[t0+d0+j] (j=0..3)
    if (tid < 128) {
        int dst = (tid * 16) ^ (((tid >> 3) & 7) << 4);
        *(short8*)((char*)Atile[t0 & 1] + dst) =
            *(const short8*)(sb + (size_t)((t0 & 127) * 1024) + tid * 8);
        #pragma unroll
        for (int j = 0; j < 4; ++j) {
            int xi = t0 + d0 + j;
            *(short8*)((char*)Btile[xi % 6] + dst) =
                *(const short8*)(sb + (size_t)((xi & 127) * 1024) + tid * 8);
        }
    }
    __syncthreads();

    int lane = tid & 63, wv = tid >> 6;
    int fr = lane & 15, kg = lane >> 4;
    int roff0 = (fr * 128 + kg * 16) ^ ((fr & 7) << 4);
    int roff1 = roff0 ^ 64;
    int myD = d0 + wv;                   // this wave's strip

    f32x4 acc = {};
    for (int stp = 0; stp < 32; ++stp) {
        int ti = t0 + stp;
        short8 sA, sB;
        if (tid < 128) {                 // issue next-step loads early (T14)
            sA = *(const short8*)(sb + (size_t)(((ti + 1) & 127) * 1024) + tid * 8);
            sB = *(const short8*)(sb + (size_t)(((ti + d0 + 4) & 127) * 1024) + tid * 8);
        }
        const char* Ab = (const char*)Atile[ti & 1];
        const char* Bb = (const char*)Btile[(ti + myD) % 6];
        short8 a0 = *(const short8*)(Ab + roff0);
        short8 a1 = *(const short8*)(Ab + roff1);
        short8 b0 = *(const short8*)(Bb + roff0);
        short8 b1 = *(const short8*)(Bb + roff1);
        acc = __builtin_amdgcn_mfma_f32_16x16x32_bf16(a0, b0, acc, 0, 0, 0);
        acc = __builtin_amdgcn_mfma_f32_16x16x32_bf16(a1, b1, acc, 0, 0, 0);
        if (tid < 128) {                 // write to slots not read this step
            int dst = (tid * 16) ^ (((tid >> 3) & 7) << 4);
            *(short8*)((char*)Atile[(ti + 1) & 1] + dst) = sA;
            *(short8*)((char*)Btile[(ti + d0 + 4) % 6] + dst) = sB;
        }
        __syncthreads();
    }

    // diagonal reduction: D[m][n], m=kg*4+q, n=fr; lag = 16*myD + n - m
    float* sc = scr[wv];
    #pragma unroll
    for (int q = 0; q < 4; ++q)
        sc[(kg * 4 + q) * 17 + fr] = acc[q];
    __syncthreads();
    if (lane < 31) {
        int d = lane - 15;
        int lag = 16 * myD + d;
        if (lag >= 1 && lag <= 1024) {
            int m0 = d < 0 ? -d : 0;
            int m1 = d < 0 ? 16 : 16 - d;
            float v = 0.f;
            for (int m = m0; m < m1; ++m) v += sc[m * 17 + m + d];
            atomicAdd(&r[(size_t)b * 1024 + (lag - 1)], v * (1.0f / 64.0f));
        }
    }
}

// ---------------- top-8 distinct candidate lags from bf16-r ----------------
__global__ __launch_bounds__(256) void k_cand(const float* __restrict__ r, int* __restrict__ cand)
{
    int b = blockIdx.x;
    __shared__ float v[1024];
    __shared__ float redv[256]; __shared__ int redi[256];
    for (int i = threadIdx.x; i < 1024; i += 256) v[i] = r[(size_t)b * 1024 + i];
    __syncthreads();
    for (int round = 0; round < 8; ++round) {
        float bv = -INFINITY; int bi = 1 << 30;
        for (int i = threadIdx.x; i < 1024; i += 256) {
            float val = v[i];
            if (val > bv) { bv = val; bi = i; }
        }
        redv[threadIdx.x] = bv; redi[threadIdx.x] = bi;
        __syncthreads();
        for (int off = 128; off; off >>= 1) {
            if (threadIdx.x < off) {
                float ov = redv[threadIdx.x + off]; int oi = redi[threadIdx.x + off];
                float mv = redv[threadIdx.x];       int mi = redi[threadIdx.x];
                if (ov > mv || (ov == mv && oi < mi)) { redv[threadIdx.x] = ov; redi[threadIdx.x] = oi; }
            }
            __syncthreads();
        }
        if (threadIdx.x == 0) {
            int lag = redi[0] + 1;
            cand[b * 8 + round] = lag;
            v[lag - 1] = -INFINITY;
        }
        __syncthreads();
    }
}

// ---------------- exact f32 rescore of 8 candidates + top-5 pair expansion + softmax ----------------
__global__ __launch_bounds__(512) void k_rescore5(const float* __restrict__ s, const int* __restrict__ cand,
                                                  int* __restrict__ selidx, float* __restrict__ selw)
{
    int b = blockIdx.x;
    int wv = threadIdx.x >> 6, lane = threadIdx.x & 63;
    const float* sb = s + (size_t)b * TT * TD;
    int lag = cand[b * 8 + wv];
    int cg = (lane & 15) * 4;
    int t0 = (lane >> 4) * 512;
    float acc = 0.f;
    #pragma unroll 8
    for (int t = t0; t < t0 + 512; ++t) {
        const float4 a = *(const float4*)(sb + ((size_t)t << 6) + cg);
        const float4 w = *(const float4*)(sb + ((size_t)((t + lag) & (TT - 1)) << 6) + cg);
        acc = fmaf(a.x, w.x, acc);
        acc = fmaf(a.y, w.y, acc);
        acc = fmaf(a.z, w.z, acc);
        acc = fmaf(a.w, w.w, acc);
    }
    #pragma unroll
    for (int mask = 32; mask; mask >>= 1) acc += __shfl_xor(acc, mask);
    __shared__ float vals[8];
    if (lane == 0) vals[wv] = acc * (1.0f / 64.0f);
    __syncthreads();
    if (threadIdx.x == 0) {
        float vv[8]; int ll[8]; bool used[8];
        #pragma unroll
        for (int i = 0; i < 8; ++i) { vv[i] = vals[i]; ll[i] = cand[b * 8 + i]; used[i] = false; }
        int s_idx[6]; float s_val[6]; int slots = 0;
        while (slots < 5) {
            float bv = -INFINITY; int bi = -1;
            for (int i = 0; i < 8; ++i) {
                if (!used[i] && (vv[i] > bv || (vv[i] == bv && ll[i] < ll[bi]))) { bv = vv[i]; bi = i; }
            }
            used[bi] = true;
            s_idx[slots] = ll[bi]; s_val[slots] = bv; slots++;
            if (slots < 5 && ll[bi] < 1024) { s_idx[slots] = 2048 - ll[bi]; s_val[slots] = bv; slots++; }
        }
        float mx = -INFINITY;
        for (int i = 0; i < 5; ++i) mx = fmaxf(mx, s_val[i]);
        float e[5], sum = 0.f;
        for (int i = 0; i < 5; ++i) { e[i] = expf(s_val[i] - mx); sum += e[i]; }
        for (int i = 0; i < 5; ++i) { selidx[b * TK + i] = s_idx[i]; selw[b * TK + i] = e[i] / sum; }
    }
}

// ---------------- conv1: 4-wave blocks, wave = 16u x 64co; LDS halo + MFMA + BN1 + GELU ----------------
__global__ __launch_bounds__(256) void k_mm1(
    const short* __restrict__ s_bf, const short* __restrict__ wtp,
    const float* __restrict__ g1, const float* __restrict__ b1,
    const float* __restrict__ m1, const float* __restrict__ v1,
    const int* __restrict__ sel, __hip_bfloat16* __restrict__ h1)
{
    int b = blockIdx.z, k = blockIdx.y;
    int p = sel[b * TK + k];
    int cyc = (TT + p - 1) / p;
    int U = cyc * p;
    int u0 = blockIdx.x * ROWS;
    if (u0 >= U) return;
    __shared__ short As[LROWS * 64];

    const short* sb = s_bf + (size_t)b * TT * TD;
    for (int q = threadIdx.x; q < LROWS * 8; q += 256) {
        int row = q >> 3, ch = (q & 7) * 8;
        int band = row / BAND, i = row - band * BAND;
        int w = u0 + (band - 1) * p - 1 + i;
        int wc = min(max(w, 0), 2 * TT - 2);
        int v = (wc < TT) ? wc : (2 * TT - 2 - wc);
        int sr = (v + p) & (TT - 1);
        short8 d = *(const short8*)(sb + (size_t)sr * TD + ch);
        int off = (row * 128 + ch * 2) ^ ((row & 7) << 4);
        *(short8*)((char*)As + off) = d;
    }
    __syncthreads();

    int lane = threadIdx.x & 63;
    int wv = threadIdx.x >> 6;
    int lr = lane & 15;
    int kg = lane >> 4;
    int lu = wv * 16 + lr;
    int u = u0 + lu;
    bool inU = (u < U);
    int r = u / p, c = u - r * p;
    bool topf = (r == 0), botf = (r == cyc - 1), leftf = (c == 0), rightf = (c == p - 1);

    f32x4 acc[4] = {};
    short8 zero = {};
    #pragma unroll
    for (int kb = 0; kb < 18; ++kb) {
        const int tap = kb >> 1, half = kb & 1;
        const int dr = tap / 3 - 1, dc = tap % 3 - 1;
        int ldsrow = (dr + 1) * BAND + lu + 1 + dc;
        int off = (ldsrow * 128 + half * 64 + kg * 16) ^ ((ldsrow & 7) << 4);
        short8 a = *(const short8*)((const char*)As + off);
        bool valid = inU
                   && !(dr == -1 && topf) && !(dr == 1 && botf)
                   && !(dc == -1 && leftf) && !(dc == 1 && rightf);
        if (!valid) a = zero;
        #pragma unroll
        for (int nt = 0; nt < 4; ++nt) {
            short8 bq = *(const short8*)(wtp + (size_t)(kb * 4 + nt) * 512 + lane * 8);
            acc[nt] = __builtin_amdgcn_mfma_f32_16x16x32_bf16(a, bq, acc[nt], 0, 0, 0);
        }
    }
    __hip_bfloat16* ho = h1 + (size_t)(b * TK + k) * (UMAX * TD);
    #pragma unroll
    for (int nt = 0; nt < 4; ++nt) {
        int co = nt * 16 + lr;
        float scale = g1[co] * rsqrtf(v1[co] + EPSBN);
        float bias = b1[co] - m1[co] * scale;
        #pragma unroll
        for (int q = 0; q < 4; ++q) {
            int uo = u0 + wv * 16 + kg * 4 + q;
            if (uo < U) {
                float z = acc[nt][q] * scale + bias;
                float ge = 0.5f * z * (1.0f + erff(z * 0.70710678118654752f));
                ho[(size_t)uo * TD + co] = __float2bfloat16(ge);
            }
        }
    }
}

// ---------------- conv2 fused over k: 4-wave blocks (wave = 16u x 16co), dbuf LDS, no atomics ----------------
__global__ __launch_bounds__(256) void k_mm2f(
    const short* __restrict__ h1, const short* __restrict__ wtp,
    const float* __restrict__ s,
    const float* __restrict__ g2, const float* __restrict__ b2,
    const float* __restrict__ m2, const float* __restrict__ v2,
    const int* __restrict__ sel, const float* __restrict__ selw,
    float* __restrict__ out)
{
    int b = blockIdx.y;
    int u0 = blockIdx.x * ROWS2;                      // < 2048
    int tid = threadIdx.x;
    __shared__ short As[2 * LROWS2 * 64];

    int lane = tid & 63, wv = tid >> 6, lr = lane & 15, kg = lane >> 4;
    int u = u0 + lr;
    const float* sb = s + (size_t)b * TT * TD;

    f32x4 accT = {};
    float gacc[4] = {0.f, 0.f, 0.f, 0.f};
    short8 sreg[2];
    short8 zero = {};

    // prologue: stage phase 0 into buffer 0
    {
        int p0 = sel[b * TK];
        const short* hb = h1 + (size_t)(b * TK) * (UMAX * TD);
        #pragma unroll
        for (int it = 0; it < 2; ++it) {
            int q = tid + it * 256;
            if (q < SH8) {
                int row = q >> 3, ch = (q & 7) * 8;
                int band = row / BAND2, i = row - band * BAND2;
                int w = u0 + (band - 1) * p0 - 1 + i;
                int wc = min(max(w, 0), UMAX - 1);
                short8 d = *(const short8*)(hb + (size_t)wc * TD + ch);
                int off = (row * 128 + ch * 2) ^ ((row & 7) << 4);
                *(short8*)((char*)As + off) = d;
            }
        }
    }
    __syncthreads();

    for (int k = 0; k < TK; ++k) {
        int p = sel[b * TK + k];
        float wk = selw[b * TK + k];
        int cyc = (TT + p - 1) / p;
        if (k < TK - 1) {
            int pn = sel[b * TK + k + 1];
            const short* hb = h1 + (size_t)(b * TK + k + 1) * (UMAX * TD);
            #pragma unroll
            for (int it = 0; it < 2; ++it) {
                int q = tid + it * 256;
                if (q < SH8) {
                    int row = q >> 3, ch = (q & 7) * 8;
                    int band = row / BAND2, i = row - band * BAND2;
                    int w = u0 + (band - 1) * pn - 1 + i;
                    int wc = min(max(w, 0), UMAX - 1);
                    sreg[it] = *(const short8*)(hb + (size_t)wc * TD + ch);
                }
            }
        }
        const char* Ab = (const char*)As + (k & 1) * BUFB;
        int r = u / p, c = u - r * p;
        bool topf = (r == 0), botf = (r == cyc - 1), leftf = (c == 0), rightf = (c == p - 1);
        f32x4 accP[2] = {};
        #pragma unroll
        for (int kb = 0; kb < 18; ++kb) {
            const int tap = kb >> 1, half = kb & 1;
            const int dr = tap / 3 - 1, dc = tap % 3 - 1;
            int ldsrow = (dr + 1) * BAND2 + lr + 1 + dc;
            int off = (ldsrow * 128 + half * 64 + kg * 16) ^ ((ldsrow & 7) << 4);
            short8 a = *(const short8*)(Ab + off);
            bool valid = !(dr == -1 && topf) && !(dr == 1 && botf)
                       && !(dc == -1 && leftf) && !(dc == 1 && rightf);
            if (!valid) a = zero;
            short8 bq = *(const short8*)(wtp + (size_t)(kb * 4 + wv) * 512 + lane * 8);
            accP[kb & 1] = __builtin_amdgcn_mfma_f32_16x16x32_bf16(a, bq, accP[kb & 1], 0, 0, 0);
        }
        #pragma unroll
        for (int e = 0; e < 4; ++e) accT[e] += wk * (accP[0][e] + accP[1][e]);
        #pragma unroll
        for (int q = 0; q < 4; ++q) {
            int uo = u0 + kg * 4 + q;
            int sr = (uo + p) & (TT - 1);
            gacc[q] = fmaf(wk, sb[(size_t)sr * TD + wv * 16 + lr], gacc[q]);
        }
        __syncthreads();
        if (k < TK - 1) {
            char* Aw = (char*)As + ((k + 1) & 1) * BUFB;
            #pragma unroll
            for (int it = 0; it < 2; ++it) {
                int q = tid + it * 256;
                if (q < SH8) {
                    int row = q >> 3, ch = (q & 7) * 8;
                    int off = (row * 128 + ch * 2) ^ ((row & 7) << 4);
                    *(short8*)(Aw + off) = sreg[it];
                }
            }
            __syncthreads();
        }
    }

    float* ob = out + (size_t)b * TT * TD;
    int co = wv * 16 + lr;
    float scale = g2[co] * rsqrtf(v2[co] + EPSBN);
    float bias = b2[co] - m2[co] * scale;
    #pragma unroll
    for (int q = 0; q < 4; ++q) {
        int uo = u0 + kg * 4 + q;
        size_t idx = (size_t)uo * TD + co;
        ob[idx] = ob[idx] + gacc[q] + scale * accT[q] + bias;
    }
}

extern "C" void kernel_launch(void* const* d_in, const int* in_sizes, int n_in,
                              void* d_out, int out_size, void* d_ws, size_t ws_size,
                              hipStream_t stream)
{
    const float* x  = (const float*)d_in[0];
    const float* w1 = (const float*)d_in[1];
    const float* w2 = (const float*)d_in[2];
    const float* g1 = (const float*)d_in[3];
    const float* b1 = (const float*)d_in[4];
    const float* m1 = (const float*)d_in[5];
    const float* v1 = (const float*)d_in[6];
    const float* g2 = (const float*)d_in[7];
    const float* b2 = (const float*)d_in[8];
    const float* m2 = (const float*)d_in[9];
    const float* v2 = (const float*)d_in[10];

    float* ws    = (float*)d_ws;
    float* s     = ws + OFF_S;
    __hip_bfloat16* sbf = (__hip_bfloat16*)(ws + OFF_SBF);
    float* r     = ws + OFF_R;
    int*   sel   = (int*)(ws + OFF_IDX);
    float* selw  = ws + OFF_W;
    __hip_bfloat16* wt1 = (__hip_bfloat16*)(ws + OFF_WT1);
    __hip_bfloat16* wt2 = (__hip_bfloat16*)(ws + OFF_WT2);
    __hip_bfloat16* h1  = (__hip_bfloat16*)(ws + OFF_H1);
    int*   cand  = (int*)(ws + OFF_CAND);
    float* out   = (float*)d_out;

    k_trend   <<<dim3(400),         dim3(256), 0, stream>>>(x, out, s, sbf, w1, w2, wt1, wt2, r);
    k_ac_mfma <<<dim3(544),         dim3(256), 0, stream>>>((const short*)sbf, r);
    k_cand    <<<dim3(TB),          dim3(256), 0, stream>>>(r, cand);
    k_rescore5<<<dim3(TB),          dim3(512), 0, stream>>>(s, cand, sel, selw);
    k_mm1     <<<dim3(64, TK, TB),  dim3(256), 0, stream>>>((const short*)sbf, (const short*)wt1,
                                                            g1, b1, m1, v1, sel, h1);
    k_mm2f    <<<dim3(128, TB),     dim3(256), 0, stream>>>((const short*)h1, (const short*)wt2, s,
                                                            g2, b2, m2, v2, sel, selw, out);
}

// Round 19
// 121.774 us; speedup vs baseline: 1.3481x; 1.3481x over previous
//
#include <hip/hip_runtime.h>
#include <hip/hip_bf16.h>
#include <math.h>

#define TB 8
#define TT 2048
#define TD 64
#define TK 5
#define TPAD 12
#define EPSBN 1e-5f
#define UMAX 4096

#define ROWS 64          // mm1: output rows per block (4 waves x 16)
#define BAND 66          // ROWS + 2 halo
#define LROWS 198        // 3 bands

// mm2f geometry
#define ROWS2 16
#define BAND2 18
#define LROWS2 54
#define SH8   432
#define BUFB  6912

#define ACG 17           // strip groups (4 strips/block -> 68 >= 65 needed)

typedef __attribute__((ext_vector_type(8))) short short8;
typedef __attribute__((ext_vector_type(4))) float f32x4;

// ws layout (float offsets)
#define OFF_S     0
#define OFF_SBF   1048576
#define OFF_R     1572864
#define OFF_IDX   1581056
#define OFF_W     1581096
#define OFF_WT1   1581136
#define OFF_WT2   1599568
#define OFF_H1    1618000
#define OFF_CAND  6860880
#define OFF_VALS  6860944
// end 6861008 floats = 27.4 MB

// ---------------- fused: trend/seasonal (sliding window) + weight repack + r zero ----------------
__global__ __launch_bounds__(256) void k_trend(const float* __restrict__ x,
                                               float* __restrict__ out, float* __restrict__ s,
                                               __hip_bfloat16* __restrict__ sbf,
                                               const float* __restrict__ w1, const float* __restrict__ w2,
                                               __hip_bfloat16* __restrict__ wt1, __hip_bfloat16* __restrict__ wt2,
                                               float* __restrict__ r)
{
    if (blockIdx.x >= 256) {
        int d = (blockIdx.x - 256) * 256 + threadIdx.x;
        if (d < TB * 1024) r[d] = 0.f;             // zero autocorr accumulator (replay-safe)
        if (d < 36864) {
            int j = d & 7, l = (d >> 3) & 63, nt = (d >> 9) & 3, kb = d >> 11;
            int tap = kb >> 1, half = kb & 1;
            int co = nt * 16 + (l & 15);
            int ci = half * 32 + (l >> 4) * 8 + j;
            int src = (co * 64 + ci) * 9 + tap;
            wt1[d] = __float2bfloat16(w1[src]);
            wt2[d] = __float2bfloat16(w2[src]);
        }
        return;
    }
    int gid = blockIdx.x * 256 + threadIdx.x;      // 65536 threads
    int c = gid & 63;
    int tblk = (gid >> 6) & 127;
    int b = gid >> 13;
    int t0 = tblk * 16;
    const float* base = x + (size_t)b * TT * TD + c;
    float sum = 0.f;
    for (int tt = t0 - TPAD; tt <= t0 + TPAD; ++tt)
        if (tt >= 0 && tt < TT) sum += base[(size_t)tt * TD];
    size_t o = (size_t)b * TT * TD + (size_t)t0 * TD + c;
    #pragma unroll
    for (int i = 0; i < 16; ++i) {
        int t = t0 + i;
        int lo = t - TPAD; if (lo < 0) lo = 0;
        int hi = t + TPAD; if (hi > TT - 1) hi = TT - 1;
        float tr = sum / (float)(hi - lo + 1);
        float xv = base[(size_t)t * TD];
        out[o] = xv + tr;
        float sv = xv - tr;
        s[o] = sv;
        sbf[o] = __float2bfloat16(sv);
        int addt = t + TPAD + 1, subt = t - TPAD;
        if (addt < TT) sum += base[(size_t)addt * TD];
        if (subt >= 0) sum -= base[(size_t)subt * TD];
        o += TD;
    }
}

// ---------------- autocorr via MFMA strips (bf16 in, f32 acc) ----------------
__global__ __launch_bounds__(256) void k_ac_mfma(const short* __restrict__ sbf16, float* __restrict__ r)
{
    int id = blockIdx.x;
    int b = id & 7;
    int slot = id >> 3;                  // 0..67
    int g = slot % ACG;                  // 0..16
    int qq = slot / ACG;                 // 0..3
    int d0 = g * 4;
    int t0 = qq * 32;
    const short* sb = sbf16 + (size_t)b * TT * TD;

    __shared__ short Atile[2][1024];
    __shared__ short Btile[6][1024];
    __shared__ float scr[4][16 * 17];

    int tid = threadIdx.x;
    if (tid < 128) {
        int dst = (tid * 16) ^ (((tid >> 3) & 7) << 4);
        *(short8*)((char*)Atile[t0 & 1] + dst) =
            *(const short8*)(sb + (size_t)((t0 & 127) * 1024) + tid * 8);
        #pragma unroll
        for (int j = 0; j < 4; ++j) {
            int xi = t0 + d0 + j;
            *(short8*)((char*)Btile[xi % 6] + dst) =
                *(const short8*)(sb + (size_t)((xi & 127) * 1024) + tid * 8);
        }
    }
    __syncthreads();

    int lane = tid & 63, wv = tid >> 6;
    int fr = lane & 15, kg = lane >> 4;
    int roff0 = (fr * 128 + kg * 16) ^ ((fr & 7) << 4);
    int roff1 = roff0 ^ 64;
    int myD = d0 + wv;

    f32x4 acc = {};
    for (int stp = 0; stp < 32; ++stp) {
        int ti = t0 + stp;
        short8 sA, sB;
        if (tid < 128) {
            sA = *(const short8*)(sb + (size_t)(((ti + 1) & 127) * 1024) + tid * 8);
            sB = *(const short8*)(sb + (size_t)(((ti + d0 + 4) & 127) * 1024) + tid * 8);
        }
        const char* Ab = (const char*)Atile[ti & 1];
        const char* Bb = (const char*)Btile[(ti + myD) % 6];
        short8 a0 = *(const short8*)(Ab + roff0);
        short8 a1 = *(const short8*)(Ab + roff1);
        short8 b0 = *(const short8*)(Bb + roff0);
        short8 b1 = *(const short8*)(Bb + roff1);
        acc = __builtin_amdgcn_mfma_f32_16x16x32_bf16(a0, b0, acc, 0, 0, 0);
        acc = __builtin_amdgcn_mfma_f32_16x16x32_bf16(a1, b1, acc, 0, 0, 0);
        if (tid < 128) {
            int dst = (tid * 16) ^ (((tid >> 3) & 7) << 4);
            *(short8*)((char*)Atile[(ti + 1) & 1] + dst) = sA;
            *(short8*)((char*)Btile[(ti + d0 + 4) % 6] + dst) = sB;
        }
        __syncthreads();
    }

    float* sc = scr[wv];
    #pragma unroll
    for (int q = 0; q < 4; ++q)
        sc[(kg * 4 + q) * 17 + fr] = acc[q];
    __syncthreads();
    if (lane < 31) {
        int d = lane - 15;
        int lag = 16 * myD + d;
        if (lag >= 1 && lag <= 1024) {
            int m0 = d < 0 ? -d : 0;
            int m1 = d < 0 ? 16 : 16 - d;
            float v = 0.f;
            for (int m = m0; m < m1; ++m) v += sc[m * 17 + m + d];
            atomicAdd(&r[(size_t)b * 1024 + (lag - 1)], v * (1.0f / 64.0f));
        }
    }
}

// ---------------- top-8 distinct candidate lags from bf16-r ----------------
__global__ __launch_bounds__(256) void k_cand(const float* __restrict__ r, int* __restrict__ cand)
{
    int b = blockIdx.x;
    __shared__ float v[1024];
    __shared__ float redv[256]; __shared__ int redi[256];
    for (int i = threadIdx.x; i < 1024; i += 256) v[i] = r[(size_t)b * 1024 + i];
    __syncthreads();
    for (int round = 0; round < 8; ++round) {
        float bv = -INFINITY; int bi = 1 << 30;
        for (int i = threadIdx.x; i < 1024; i += 256) {
            float val = v[i];
            if (val > bv) { bv = val; bi = i; }
        }
        redv[threadIdx.x] = bv; redi[threadIdx.x] = bi;
        __syncthreads();
        for (int off = 128; off; off >>= 1) {
            if (threadIdx.x < off) {
                float ov = redv[threadIdx.x + off]; int oi = redi[threadIdx.x + off];
                float mv = redv[threadIdx.x];       int mi = redi[threadIdx.x];
                if (ov > mv || (ov == mv && oi < mi)) { redv[threadIdx.x] = ov; redi[threadIdx.x] = oi; }
            }
            __syncthreads();
        }
        if (threadIdx.x == 0) {
            int lag = redi[0] + 1;
            cand[b * 8 + round] = lag;
            v[lag - 1] = -INFINITY;
        }
        __syncthreads();
    }
}

// ---------------- exact f32 rescore: one block per (candidate, batch) ----------------
__global__ __launch_bounds__(256) void k_rescore(const float* __restrict__ s, const int* __restrict__ cand,
                                                 float* __restrict__ vals)
{
    int ci = blockIdx.x;                 // 0..7
    int b = blockIdx.y;
    int lag = cand[b * 8 + ci];
    const float* sb = s + (size_t)b * TT * TD;
    int cg = (threadIdx.x & 15) * 4;
    int t0 = (threadIdx.x >> 4) * 128;
    float acc = 0.f;
    #pragma unroll 8
    for (int t = t0; t < t0 + 128; ++t) {
        const float4 a = *(const float4*)(sb + ((size_t)t << 6) + cg);
        const float4 w = *(const float4*)(sb + ((size_t)((t + lag) & (TT - 1)) << 6) + cg);
        acc = fmaf(a.x, w.x, acc);
        acc = fmaf(a.y, w.y, acc);
        acc = fmaf(a.z, w.z, acc);
        acc = fmaf(a.w, w.w, acc);
    }
    __shared__ float red[256];
    red[threadIdx.x] = acc;
    __syncthreads();
    for (int off = 128; off; off >>= 1) {
        if (threadIdx.x < off) red[threadIdx.x] += red[threadIdx.x + off];
        __syncthreads();
    }
    if (threadIdx.x == 0) vals[b * 8 + ci] = red[0] * (1.0f / 64.0f);
}

// ---------------- serial top-5 pair expansion + softmax over 8 rescored candidates ----------------
__global__ __launch_bounds__(64) void k_sel(const float* __restrict__ vals, const int* __restrict__ cand,
                                            int* __restrict__ selidx, float* __restrict__ selw)
{
    int b = blockIdx.x;
    if (threadIdx.x != 0) return;
    float vv[8]; int ll[8]; bool used[8];
    #pragma unroll
    for (int i = 0; i < 8; ++i) { vv[i] = vals[b * 8 + i]; ll[i] = cand[b * 8 + i]; used[i] = false; }
    int s_idx[6]; float s_val[6]; int slots = 0;
    while (slots < 5) {
        float bv = -INFINITY; int bi = -1;
        for (int i = 0; i < 8; ++i) {
            if (!used[i] && (vv[i] > bv || (vv[i] == bv && bi >= 0 && ll[i] < ll[bi]))) { bv = vv[i]; bi = i; }
        }
        used[bi] = true;
        s_idx[slots] = ll[bi]; s_val[slots] = bv; slots++;
        if (slots < 5 && ll[bi] < 1024) { s_idx[slots] = 2048 - ll[bi]; s_val[slots] = bv; slots++; }
    }
    float mx = -INFINITY;
    for (int i = 0; i < 5; ++i) mx = fmaxf(mx, s_val[i]);
    float e[5], sum = 0.f;
    for (int i = 0; i < 5; ++i) { e[i] = expf(s_val[i] - mx); sum += e[i]; }
    for (int i = 0; i < 5; ++i) { selidx[b * TK + i] = s_idx[i]; selw[b * TK + i] = e[i] / sum; }
}

// ---------------- conv1: 4-wave blocks, wave = 16u x 64co; LDS halo + MFMA + BN1 + GELU ----------------
__global__ __launch_bounds__(256) void k_mm1(
    const short* __restrict__ s_bf, const short* __restrict__ wtp,
    const float* __restrict__ g1, const float* __restrict__ b1,
    const float* __restrict__ m1, const float* __restrict__ v1,
    const int* __restrict__ sel, __hip_bfloat16* __restrict__ h1)
{
    int b = blockIdx.z, k = blockIdx.y;
    int p = sel[b * TK + k];
    int cyc = (TT + p - 1) / p;
    int U = cyc * p;
    int u0 = blockIdx.x * ROWS;
    if (u0 >= U) return;
    __shared__ short As[LROWS * 64];

    const short* sb = s_bf + (size_t)b * TT * TD;
    for (int q = threadIdx.x; q < LROWS * 8; q += 256) {
        int row = q >> 3, ch = (q & 7) * 8;
        int band = row / BAND, i = row - band * BAND;
        int w = u0 + (band - 1) * p - 1 + i;
        int wc = min(max(w, 0), 2 * TT - 2);
        int v = (wc < TT) ? wc : (2 * TT - 2 - wc);
        int sr = (v + p) & (TT - 1);
        short8 d = *(const short8*)(sb + (size_t)sr * TD + ch);
        int off = (row * 128 + ch * 2) ^ ((row & 7) << 4);
        *(short8*)((char*)As + off) = d;
    }
    __syncthreads();

    int lane = threadIdx.x & 63;
    int wv = threadIdx.x >> 6;
    int lr = lane & 15;
    int kg = lane >> 4;
    int lu = wv * 16 + lr;
    int u = u0 + lu;
    bool inU = (u < U);
    int r = u / p, c = u - r * p;
    bool topf = (r == 0), botf = (r == cyc - 1), leftf = (c == 0), rightf = (c == p - 1);

    f32x4 acc[4] = {};
    short8 zero = {};
    #pragma unroll
    for (int kb = 0; kb < 18; ++kb) {
        const int tap = kb >> 1, half = kb & 1;
        const int dr = tap / 3 - 1, dc = tap % 3 - 1;
        int ldsrow = (dr + 1) * BAND + lu + 1 + dc;
        int off = (ldsrow * 128 + half * 64 + kg * 16) ^ ((ldsrow & 7) << 4);
        short8 a = *(const short8*)((const char*)As + off);
        bool valid = inU
                   && !(dr == -1 && topf) && !(dr == 1 && botf)
                   && !(dc == -1 && leftf) && !(dc == 1 && rightf);
        if (!valid) a = zero;
        #pragma unroll
        for (int nt = 0; nt < 4; ++nt) {
            short8 bq = *(const short8*)(wtp + (size_t)(kb * 4 + nt) * 512 + lane * 8);
            acc[nt] = __builtin_amdgcn_mfma_f32_16x16x32_bf16(a, bq, acc[nt], 0, 0, 0);
        }
    }
    __hip_bfloat16* ho = h1 + (size_t)(b * TK + k) * (UMAX * TD);
    #pragma unroll
    for (int nt = 0; nt < 4; ++nt) {
        int co = nt * 16 + lr;
        float scale = g1[co] * rsqrtf(v1[co] + EPSBN);
        float bias = b1[co] - m1[co] * scale;
        #pragma unroll
        for (int q = 0; q < 4; ++q) {
            int uo = u0 + wv * 16 + kg * 4 + q;
            if (uo < U) {
                float z = acc[nt][q] * scale + bias;
                float ge = 0.5f * z * (1.0f + erff(z * 0.70710678118654752f));
                ho[(size_t)uo * TD + co] = __float2bfloat16(ge);
            }
        }
    }
}

// ---------------- conv2 fused over k: 4-wave blocks (wave = 16u x 16co), dbuf LDS, no atomics ----------------
__global__ __launch_bounds__(256) void k_mm2f(
    const short* __restrict__ h1, const short* __restrict__ wtp,
    const float* __restrict__ s,
    const float* __restrict__ g2, const float* __restrict__ b2,
    const float* __restrict__ m2, const float* __restrict__ v2,
    const int* __restrict__ sel, const float* __restrict__ selw,
    float* __restrict__ out)
{
    int b = blockIdx.y;
    int u0 = blockIdx.x * ROWS2;                      // < 2048
    int tid = threadIdx.x;
    __shared__ short As[2 * LROWS2 * 64];

    int lane = tid & 63, wv = tid >> 6, lr = lane & 15, kg = lane >> 4;
    int u = u0 + lr;
    const float* sb = s + (size_t)b * TT * TD;

    f32x4 accT = {};
    float gacc[4] = {0.f, 0.f, 0.f, 0.f};
    short8 sreg[2];
    short8 zero = {};

    {
        int p0 = sel[b * TK];
        const short* hb = h1 + (size_t)(b * TK) * (UMAX * TD);
        #pragma unroll
        for (int it = 0; it < 2; ++it) {
            int q = tid + it * 256;
            if (q < SH8) {
                int row = q >> 3, ch = (q & 7) * 8;
                int band = row / BAND2, i = row - band * BAND2;
                int w = u0 + (band - 1) * p0 - 1 + i;
                int wc = min(max(w, 0), UMAX - 1);
                short8 d = *(const short8*)(hb + (size_t)wc * TD + ch);
                int off = (row * 128 + ch * 2) ^ ((row & 7) << 4);
                *(short8*)((char*)As + off) = d;
            }
        }
    }
    __syncthreads();

    for (int k = 0; k < TK; ++k) {
        int p = sel[b * TK + k];
        float wk = selw[b * TK + k];
        int cyc = (TT + p - 1) / p;
        if (k < TK - 1) {
            int pn = sel[b * TK + k + 1];
            const short* hb = h1 + (size_t)(b * TK + k + 1) * (UMAX * TD);
            #pragma unroll
            for (int it = 0; it < 2; ++it) {
                int q = tid + it * 256;
                if (q < SH8) {
                    int row = q >> 3, ch = (q & 7) * 8;
                    int band = row / BAND2, i = row - band * BAND2;
                    int w = u0 + (band - 1) * pn - 1 + i;
                    int wc = min(max(w, 0), UMAX - 1);
                    sreg[it] = *(const short8*)(hb + (size_t)wc * TD + ch);
                }
            }
        }
        const char* Ab = (const char*)As + (k & 1) * BUFB;
        int r = u / p, c = u - r * p;
        bool topf = (r == 0), botf = (r == cyc - 1), leftf = (c == 0), rightf = (c == p - 1);
        f32x4 accP[2] = {};
        #pragma unroll
        for (int kb = 0; kb < 18; ++kb) {
            const int tap = kb >> 1, half = kb & 1;
            const int dr = tap / 3 - 1, dc = tap % 3 - 1;
            int ldsrow = (dr + 1) * BAND2 + lr + 1 + dc;
            int off = (ldsrow * 128 + half * 64 + kg * 16) ^ ((ldsrow & 7) << 4);
            short8 a = *(const short8*)(Ab + off);
            bool valid = !(dr == -1 && topf) && !(dr == 1 && botf)
                       && !(dc == -1 && leftf) && !(dc == 1 && rightf);
            if (!valid) a = zero;
            short8 bq = *(const short8*)(wtp + (size_t)(kb * 4 + wv) * 512 + lane * 8);
            accP[kb & 1] = __builtin_amdgcn_mfma_f32_16x16x32_bf16(a, bq, accP[kb & 1], 0, 0, 0);
        }
        #pragma unroll
        for (int e = 0; e < 4; ++e) accT[e] += wk * (accP[0][e] + accP[1][e]);
        #pragma unroll
        for (int q = 0; q < 4; ++q) {
            int uo = u0 + kg * 4 + q;
            int sr = (uo + p) & (TT - 1);
            gacc[q] = fmaf(wk, sb[(size_t)sr * TD + wv * 16 + lr], gacc[q]);
        }
        __syncthreads();
        if (k < TK - 1) {
            char* Aw = (char*)As + ((k + 1) & 1) * BUFB;
            #pragma unroll
            for (int it = 0; it < 2; ++it) {
                int q = tid + it * 256;
                if (q < SH8) {
                    int row = q >> 3, ch = (q & 7) * 8;
                    int off = (row * 128 + ch * 2) ^ ((row & 7) << 4);
                    *(short8*)(Aw + off) = sreg[it];
                }
            }
            __syncthreads();
        }
    }

    float* ob = out + (size_t)b * TT * TD;
    int co = wv * 16 + lr;
    float scale = g2[co] * rsqrtf(v2[co] + EPSBN);
    float bias = b2[co] - m2[co] * scale;
    #pragma unroll
    for (int q = 0; q < 4; ++q) {
        int uo = u0 + kg * 4 + q;
        size_t idx = (size_t)uo * TD + co;
        ob[idx] = ob[idx] + gacc[q] + scale * accT[q] + bias;
    }
}

extern "C" void kernel_launch(void* const* d_in, const int* in_sizes, int n_in,
                              void* d_out, int out_size, void* d_ws, size_t ws_size,
                              hipStream_t stream)
{
    const float* x  = (const float*)d_in[0];
    const float* w1 = (const float*)d_in[1];
    const float* w2 = (const float*)d_in[2];
    const float* g1 = (const float*)d_in[3];
    const float* b1 = (const float*)d_in[4];
    const float* m1 = (const float*)d_in[5];
    const float* v1 = (const float*)d_in[6];
    const float* g2 = (const float*)d_in[7];
    const float* b2 = (const float*)d_in[8];
    const float* m2 = (const float*)d_in[9];
    const float* v2 = (const float*)d_in[10];

    float* ws    = (float*)d_ws;
    float* s     = ws + OFF_S;
    __hip_bfloat16* sbf = (__hip_bfloat16*)(ws + OFF_SBF);
    float* r     = ws + OFF_R;
    int*   sel   = (int*)(ws + OFF_IDX);
    float* selw  = ws + OFF_W;
    __hip_bfloat16* wt1 = (__hip_bfloat16*)(ws + OFF_WT1);
    __hip_bfloat16* wt2 = (__hip_bfloat16*)(ws + OFF_WT2);
    __hip_bfloat16* h1  = (__hip_bfloat16*)(ws + OFF_H1);
    int*   cand  = (int*)(ws + OFF_CAND);
    float* vals  = ws + OFF_VALS;
    float* out   = (float*)d_out;

    k_trend   <<<dim3(400),         dim3(256), 0, stream>>>(x, out, s, sbf, w1, w2, wt1, wt2, r);
    k_ac_mfma <<<dim3(544),         dim3(256), 0, stream>>>((const short*)sbf, r);
    k_cand    <<<dim3(TB),          dim3(256), 0, stream>>>(r, cand);
    k_rescore <<<dim3(8, TB),       dim3(256), 0, stream>>>(s, cand, vals);
    k_sel     <<<dim3(TB),          dim3(64),  0, stream>>>(vals, cand, sel, selw);
    k_mm1     <<<dim3(64, TK, TB),  dim3(256), 0, stream>>>((const short*)sbf, (const short*)wt1,
                                                            g1, b1, m1, v1, sel, h1);
    k_mm2f    <<<dim3(128, TB),     dim3(256), 0, stream>>>((const short*)h1, (const short*)wt2, s,
                                                            g2, b2, m2, v2, sel, selw, out);
}

// Round 20
// 114.158 us; speedup vs baseline: 1.4380x; 1.0667x over previous
//
#include <hip/hip_runtime.h>
#include <hip/hip_bf16.h>
#include <math.h>

#define TB 8
#define TT 2048
#define TD 64
#define TK 5
#define TPAD 12
#define EPSBN 1e-5f
#define UMAX 4096

#define ROWS1 128        // mm1: output rows per block (4 waves x 32)
#define BAND1 130
#define LROWS1 390

// mm2f geometry
#define ROWS2 16
#define BAND2 18
#define LROWS2 54
#define SH8   432
#define BUFB  6912

#define ACG 17           // strip groups (4 strips/block -> 68 >= 65 needed)

typedef __attribute__((ext_vector_type(8))) short short8;
typedef __attribute__((ext_vector_type(4))) float f32x4;

// ws layout (float offsets)
#define OFF_S     0
#define OFF_SBF   1048576
#define OFF_R     1572864
#define OFF_IDX   1581056
#define OFF_W     1581096
#define OFF_WT1   1581136
#define OFF_WT2   1599568
#define OFF_H1    1618000
#define OFF_CAND  6860880
#define OFF_VALS  6860944
// end 6861008 floats = 27.4 MB

// ---------------- fused: trend/seasonal + weight repack + r/vals zero ----------------
__global__ __launch_bounds__(256) void k_trend(const float* __restrict__ x,
                                               float* __restrict__ out, float* __restrict__ s,
                                               __hip_bfloat16* __restrict__ sbf,
                                               const float* __restrict__ w1, const float* __restrict__ w2,
                                               __hip_bfloat16* __restrict__ wt1, __hip_bfloat16* __restrict__ wt2,
                                               float* __restrict__ r, float* __restrict__ vals)
{
    if (blockIdx.x >= 256) {
        int d = (blockIdx.x - 256) * 256 + threadIdx.x;
        if (d < TB * 1024) r[d] = 0.f;             // zero autocorr accumulator (replay-safe)
        if (d < TB * 8) vals[d] = 0.f;             // zero rescore accumulator
        if (d < 36864) {
            int j = d & 7, l = (d >> 3) & 63, nt = (d >> 9) & 3, kb = d >> 11;
            int tap = kb >> 1, half = kb & 1;
            int co = nt * 16 + (l & 15);
            int ci = half * 32 + (l >> 4) * 8 + j;
            int src = (co * 64 + ci) * 9 + tap;
            wt1[d] = __float2bfloat16(w1[src]);
            wt2[d] = __float2bfloat16(w2[src]);
        }
        return;
    }
    int gid = blockIdx.x * 256 + threadIdx.x;      // 65536 threads
    int c = gid & 63;
    int tblk = (gid >> 6) & 127;
    int b = gid >> 13;
    int t0 = tblk * 16;
    const float* base = x + (size_t)b * TT * TD + c;
    float sum = 0.f;
    for (int tt = t0 - TPAD; tt <= t0 + TPAD; ++tt)
        if (tt >= 0 && tt < TT) sum += base[(size_t)tt * TD];
    size_t o = (size_t)b * TT * TD + (size_t)t0 * TD + c;
    #pragma unroll
    for (int i = 0; i < 16; ++i) {
        int t = t0 + i;
        int lo = t - TPAD; if (lo < 0) lo = 0;
        int hi = t + TPAD; if (hi > TT - 1) hi = TT - 1;
        float tr = sum / (float)(hi - lo + 1);
        float xv = base[(size_t)t * TD];
        out[o] = xv + tr;
        float sv = xv - tr;
        s[o] = sv;
        sbf[o] = __float2bfloat16(sv);
        int addt = t + TPAD + 1, subt = t - TPAD;
        if (addt < TT) sum += base[(size_t)addt * TD];
        if (subt >= 0) sum -= base[(size_t)subt * TD];
        o += TD;
    }
}

// ---------------- autocorr via MFMA strips (bf16 in, f32 acc) ----------------
__global__ __launch_bounds__(256) void k_ac_mfma(const short* __restrict__ sbf16, float* __restrict__ r)
{
    int id = blockIdx.x;
    int b = id & 7;
    int slot = id >> 3;                  // 0..67
    int g = slot % ACG;                  // 0..16
    int qq = slot / ACG;                 // 0..3
    int d0 = g * 4;
    int t0 = qq * 32;
    const short* sb = sbf16 + (size_t)b * TT * TD;

    __shared__ short Atile[2][1024];
    __shared__ short Btile[6][1024];
    __shared__ float scr[4][16 * 17];

    int tid = threadIdx.x;
    if (tid < 128) {
        int dst = (tid * 16) ^ (((tid >> 3) & 7) << 4);
        *(short8*)((char*)Atile[t0 & 1] + dst) =
            *(const short8*)(sb + (size_t)((t0 & 127) * 1024) + tid * 8);
        #pragma unroll
        for (int j = 0; j < 4; ++j) {
            int xi = t0 + d0 + j;
            *(short8*)((char*)Btile[xi % 6] + dst) =
                *(const short8*)(sb + (size_t)((xi & 127) * 1024) + tid * 8);
        }
    }
    __syncthreads();

    int lane = tid & 63, wv = tid >> 6;
    int fr = lane & 15, kg = lane >> 4;
    int roff0 = (fr * 128 + kg * 16) ^ ((fr & 7) << 4);
    int roff1 = roff0 ^ 64;
    int myD = d0 + wv;

    f32x4 acc = {};
    for (int stp = 0; stp < 32; ++stp) {
        int ti = t0 + stp;
        short8 sA, sB;
        if (tid < 128) {
            sA = *(const short8*)(sb + (size_t)(((ti + 1) & 127) * 1024) + tid * 8);
            sB = *(const short8*)(sb + (size_t)(((ti + d0 + 4) & 127) * 1024) + tid * 8);
        }
        const char* Ab = (const char*)Atile[ti & 1];
        const char* Bb = (const char*)Btile[(ti + myD) % 6];
        short8 a0 = *(const short8*)(Ab + roff0);
        short8 a1 = *(const short8*)(Ab + roff1);
        short8 b0 = *(const short8*)(Bb + roff0);
        short8 b1 = *(const short8*)(Bb + roff1);
        acc = __builtin_amdgcn_mfma_f32_16x16x32_bf16(a0, b0, acc, 0, 0, 0);
        acc = __builtin_amdgcn_mfma_f32_16x16x32_bf16(a1, b1, acc, 0, 0, 0);
        if (tid < 128) {
            int dst = (tid * 16) ^ (((tid >> 3) & 7) << 4);
            *(short8*)((char*)Atile[(ti + 1) & 1] + dst) = sA;
            *(short8*)((char*)Btile[(ti + d0 + 4) % 6] + dst) = sB;
        }
        __syncthreads();
    }

    float* sc = scr[wv];
    #pragma unroll
    for (int q = 0; q < 4; ++q)
        sc[(kg * 4 + q) * 17 + fr] = acc[q];
    __syncthreads();
    if (lane < 31) {
        int d = lane - 15;
        int lag = 16 * myD + d;
        if (lag >= 1 && lag <= 1024) {
            int m0 = d < 0 ? -d : 0;
            int m1 = d < 0 ? 16 : 16 - d;
            float v = 0.f;
            for (int m = m0; m < m1; ++m) v += sc[m * 17 + m + d];
            atomicAdd(&r[(size_t)b * 1024 + (lag - 1)], v * (1.0f / 64.0f));
        }
    }
}

// ---------------- top-8 distinct candidate lags from bf16-r ----------------
__global__ __launch_bounds__(256) void k_cand(const float* __restrict__ r, int* __restrict__ cand)
{
    int b = blockIdx.x;
    __shared__ float v[1024];
    __shared__ float redv[256]; __shared__ int redi[256];
    for (int i = threadIdx.x; i < 1024; i += 256) v[i] = r[(size_t)b * 1024 + i];
    __syncthreads();
    for (int round = 0; round < 8; ++round) {
        float bv = -INFINITY; int bi = 1 << 30;
        for (int i = threadIdx.x; i < 1024; i += 256) {
            float val = v[i];
            if (val > bv) { bv = val; bi = i; }
        }
        redv[threadIdx.x] = bv; redi[threadIdx.x] = bi;
        __syncthreads();
        for (int off = 128; off; off >>= 1) {
            if (threadIdx.x < off) {
                float ov = redv[threadIdx.x + off]; int oi = redi[threadIdx.x + off];
                float mv = redv[threadIdx.x];       int mi = redi[threadIdx.x];
                if (ov > mv || (ov == mv && oi < mi)) { redv[threadIdx.x] = ov; redi[threadIdx.x] = oi; }
            }
            __syncthreads();
        }
        if (threadIdx.x == 0) {
            int lag = redi[0] + 1;
            cand[b * 8 + round] = lag;
            v[lag - 1] = -INFINITY;
        }
        __syncthreads();
    }
}

// ---------------- exact f32 rescore: block per (candidate, t-quarter, batch), atomic partials ----------------
__global__ __launch_bounds__(256) void k_rescore(const float* __restrict__ s, const int* __restrict__ cand,
                                                 float* __restrict__ vals)
{
    int ci = blockIdx.x;                 // 0..7
    int tq = blockIdx.y;                 // 0..3
    int b = blockIdx.z;
    int lag = cand[b * 8 + ci];
    const float* sb = s + (size_t)b * TT * TD;
    int cg = (threadIdx.x & 15) * 4;
    int t0 = tq * 512 + (threadIdx.x >> 4) * 32;
    float acc = 0.f;
    #pragma unroll 8
    for (int t = t0; t < t0 + 32; ++t) {
        const float4 a = *(const float4*)(sb + ((size_t)t << 6) + cg);
        const float4 w = *(const float4*)(sb + ((size_t)((t + lag) & (TT - 1)) << 6) + cg);
        acc = fmaf(a.x, w.x, acc);
        acc = fmaf(a.y, w.y, acc);
        acc = fmaf(a.z, w.z, acc);
        acc = fmaf(a.w, w.w, acc);
    }
    __shared__ float red[256];
    red[threadIdx.x] = acc;
    __syncthreads();
    for (int off = 128; off; off >>= 1) {
        if (threadIdx.x < off) red[threadIdx.x] += red[threadIdx.x + off];
        __syncthreads();
    }
    if (threadIdx.x == 0) atomicAdd(&vals[b * 8 + ci], red[0] * (1.0f / 64.0f));
}

// ---------------- serial top-5 pair expansion + softmax over 8 rescored candidates ----------------
__global__ __launch_bounds__(64) void k_sel(const float* __restrict__ vals, const int* __restrict__ cand,
                                            int* __restrict__ selidx, float* __restrict__ selw)
{
    int b = blockIdx.x;
    if (threadIdx.x != 0) return;
    float vv[8]; int ll[8]; bool used[8];
    #pragma unroll
    for (int i = 0; i < 8; ++i) { vv[i] = vals[b * 8 + i]; ll[i] = cand[b * 8 + i]; used[i] = false; }
    int s_idx[6]; float s_val[6]; int slots = 0;
    while (slots < 5) {
        float bv = -INFINITY; int bi = -1;
        for (int i = 0; i < 8; ++i) {
            if (!used[i] && (vv[i] > bv || (vv[i] == bv && bi >= 0 && ll[i] < ll[bi]))) { bv = vv[i]; bi = i; }
        }
        used[bi] = true;
        s_idx[slots] = ll[bi]; s_val[slots] = bv; slots++;
        if (slots < 5 && ll[bi] < 1024) { s_idx[slots] = 2048 - ll[bi]; s_val[slots] = bv; slots++; }
    }
    float mx = -INFINITY;
    for (int i = 0; i < 5; ++i) mx = fmaxf(mx, s_val[i]);
    float e[5], sum = 0.f;
    for (int i = 0; i < 5; ++i) { e[i] = expf(s_val[i] - mx); sum += e[i]; }
    for (int i = 0; i < 5; ++i) { selidx[b * TK + i] = s_idx[i]; selw[b * TK + i] = e[i] / sum; }
}

// ---------------- conv1: 4 waves x 32 rows; LDS halo + MFMA + BN1 + GELU ----------------
__global__ __launch_bounds__(256) void k_mm1(
    const short* __restrict__ s_bf, const short* __restrict__ wtp,
    const float* __restrict__ g1, const float* __restrict__ b1,
    const float* __restrict__ m1, const float* __restrict__ v1,
    const int* __restrict__ sel, __hip_bfloat16* __restrict__ h1)
{
    int b = blockIdx.z, k = blockIdx.y;
    int p = sel[b * TK + k];
    int cyc = (TT + p - 1) / p;
    int U = cyc * p;
    int u0 = blockIdx.x * ROWS1;
    if (u0 >= U) return;
    __shared__ short As[LROWS1 * 64];              // 49920 B

    const short* sb = s_bf + (size_t)b * TT * TD;
    for (int q = threadIdx.x; q < LROWS1 * 8; q += 256) {
        int row = q >> 3, ch = (q & 7) * 8;
        int band = row / BAND1, i = row - band * BAND1;
        int w = u0 + (band - 1) * p - 1 + i;
        int wc = min(max(w, 0), 2 * TT - 2);
        int v = (wc < TT) ? wc : (2 * TT - 2 - wc);
        int sr = (v + p) & (TT - 1);
        short8 d = *(const short8*)(sb + (size_t)sr * TD + ch);
        int off = (row * 128 + ch * 2) ^ ((row & 7) << 4);
        *(short8*)((char*)As + off) = d;
    }
    __syncthreads();

    int lane = threadIdx.x & 63;
    int wv = threadIdx.x >> 6;
    int lr = lane & 15;
    int kg = lane >> 4;
    int lu[2]; bool inU[2], topf[2], botf[2], leftf[2], rightf[2];
    #pragma unroll
    for (int rs = 0; rs < 2; ++rs) {
        lu[rs] = wv * 32 + rs * 16 + lr;
        int u = u0 + lu[rs];
        inU[rs] = (u < U);
        int r = u / p, c = u - r * p;
        topf[rs] = (r == 0); botf[rs] = (r == cyc - 1);
        leftf[rs] = (c == 0); rightf[rs] = (c == p - 1);
    }

    f32x4 acc[2][4] = {};
    short8 zero = {};
    #pragma unroll
    for (int kb = 0; kb < 18; ++kb) {
        const int tap = kb >> 1, half = kb & 1;
        const int dr = tap / 3 - 1, dc = tap % 3 - 1;
        short8 a[2];
        #pragma unroll
        for (int rs = 0; rs < 2; ++rs) {
            int ldsrow = (dr + 1) * BAND1 + lu[rs] + 1 + dc;
            int off = (ldsrow * 128 + half * 64 + kg * 16) ^ ((ldsrow & 7) << 4);
            a[rs] = *(const short8*)((const char*)As + off);
            bool valid = inU[rs]
                       && !(dr == -1 && topf[rs]) && !(dr == 1 && botf[rs])
                       && !(dc == -1 && leftf[rs]) && !(dc == 1 && rightf[rs]);
            if (!valid) a[rs] = zero;
        }
        #pragma unroll
        for (int nt = 0; nt < 4; ++nt) {
            short8 bq = *(const short8*)(wtp + (size_t)(kb * 4 + nt) * 512 + lane * 8);
            #pragma unroll
            for (int rs = 0; rs < 2; ++rs)
                acc[rs][nt] = __builtin_amdgcn_mfma_f32_16x16x32_bf16(a[rs], bq, acc[rs][nt], 0, 0, 0);
        }
    }
    __hip_bfloat16* ho = h1 + (size_t)(b * TK + k) * (UMAX * TD);
    #pragma unroll
    for (int nt = 0; nt < 4; ++nt) {
        int co = nt * 16 + lr;
        float scale = g1[co] * rsqrtf(v1[co] + EPSBN);
        float bias = b1[co] - m1[co] * scale;
        #pragma unroll
        for (int rs = 0; rs < 2; ++rs) {
            int ub = u0 + wv * 32 + rs * 16 + kg * 4;
            #pragma unroll
            for (int q = 0; q < 4; ++q) {
                int uo = ub + q;
                if (uo < U) {
                    float z = acc[rs][nt][q] * scale + bias;
                    float ge = 0.5f * z * (1.0f + erff(z * 0.70710678118654752f));
                    ho[(size_t)uo * TD + co] = __float2bfloat16(ge);
                }
            }
        }
    }
}

// ---------------- conv2 fused over k: 4-wave blocks (wave = 16u x 16co), dbuf LDS, no atomics ----------------
__global__ __launch_bounds__(256) void k_mm2f(
    const short* __restrict__ h1, const short* __restrict__ wtp,
    const float* __restrict__ s,
    const float* __restrict__ g2, const float* __restrict__ b2,
    const float* __restrict__ m2, const float* __restrict__ v2,
    const int* __restrict__ sel, const float* __restrict__ selw,
    float* __restrict__ out)
{
    int b = blockIdx.y;
    int u0 = blockIdx.x * ROWS2;                      // < 2048
    int tid = threadIdx.x;
    __shared__ short As[2 * LROWS2 * 64];

    int lane = tid & 63, wv = tid >> 6, lr = lane & 15, kg = lane >> 4;
    int u = u0 + lr;
    const float* sb = s + (size_t)b * TT * TD;

    f32x4 accT = {};
    float gacc[4] = {0.f, 0.f, 0.f, 0.f};
    short8 sreg[2];
    short8 zero = {};

    {
        int p0 = sel[b * TK];
        const short* hb = h1 + (size_t)(b * TK) * (UMAX * TD);
        #pragma unroll
        for (int it = 0; it < 2; ++it) {
            int q = tid + it * 256;
            if (q < SH8) {
                int row = q >> 3, ch = (q & 7) * 8;
                int band = row / BAND2, i = row - band * BAND2;
                int w = u0 + (band - 1) * p0 - 1 + i;
                int wc = min(max(w, 0), UMAX - 1);
                short8 d = *(const short8*)(hb + (size_t)wc * TD + ch);
                int off = (row * 128 + ch * 2) ^ ((row & 7) << 4);
                *(short8*)((char*)As + off) = d;
            }
        }
    }
    __syncthreads();

    for (int k = 0; k < TK; ++k) {
        int p = sel[b * TK + k];
        float wk = selw[b * TK + k];
        int cyc = (TT + p - 1) / p;
        if (k < TK - 1) {
            int pn = sel[b * TK + k + 1];
            const short* hb = h1 + (size_t)(b * TK + k + 1) * (UMAX * TD);
            #pragma unroll
            for (int it = 0; it < 2; ++it) {
                int q = tid + it * 256;
                if (q < SH8) {
                    int row = q >> 3, ch = (q & 7) * 8;
                    int band = row / BAND2, i = row - band * BAND2;
                    int w = u0 + (band - 1) * pn - 1 + i;
                    int wc = min(max(w, 0), UMAX - 1);
                    sreg[it] = *(const short8*)(hb + (size_t)wc * TD + ch);
                }
            }
        }
        const char* Ab = (const char*)As + (k & 1) * BUFB;
        int r = u / p, c = u - r * p;
        bool topf = (r == 0), botf = (r == cyc - 1), leftf = (c == 0), rightf = (c == p - 1);
        f32x4 accP[2] = {};
        #pragma unroll
        for (int kb = 0; kb < 18; ++kb) {
            const int tap = kb >> 1, half = kb & 1;
            const int dr = tap / 3 - 1, dc = tap % 3 - 1;
            int ldsrow = (dr + 1) * BAND2 + lr + 1 + dc;
            int off = (ldsrow * 128 + half * 64 + kg * 16) ^ ((ldsrow & 7) << 4);
            short8 a = *(const short8*)(Ab + off);
            bool valid = !(dr == -1 && topf) && !(dr == 1 && botf)
                       && !(dc == -1 && leftf) && !(dc == 1 && rightf);
            if (!valid) a = zero;
            short8 bq = *(const short8*)(wtp + (size_t)(kb * 4 + wv) * 512 + lane * 8);
            accP[kb & 1] = __builtin_amdgcn_mfma_f32_16x16x32_bf16(a, bq, accP[kb & 1], 0, 0, 0);
        }
        #pragma unroll
        for (int e = 0; e < 4; ++e) accT[e] += wk * (accP[0][e] + accP[1][e]);
        #pragma unroll
        for (int q = 0; q < 4; ++q) {
            int uo = u0 + kg * 4 + q;
            int sr = (uo + p) & (TT - 1);
            gacc[q] = fmaf(wk, sb[(size_t)sr * TD + wv * 16 + lr], gacc[q]);
        }
        __syncthreads();
        if (k < TK - 1) {
            char* Aw = (char*)As + ((k + 1) & 1) * BUFB;
            #pragma unroll
            for (int it = 0; it < 2; ++it) {
                int q = tid + it * 256;
                if (q < SH8) {
                    int row = q >> 3, ch = (q & 7) * 8;
                    int off = (row * 128 + ch * 2) ^ ((row & 7) << 4);
                    *(short8*)(Aw + off) = sreg[it];
                }
            }
            __syncthreads();
        }
    }

    float* ob = out + (size_t)b * TT * TD;
    int co = wv * 16 + lr;
    float scale = g2[co] * rsqrtf(v2[co] + EPSBN);
    float bias = b2[co] - m2[co] * scale;
    #pragma unroll
    for (int q = 0; q < 4; ++q) {
        int uo = u0 + kg * 4 + q;
        size_t idx = (size_t)uo * TD + co;
        ob[idx] = ob[idx] + gacc[q] + scale * accT[q] + bias;
    }
}

extern "C" void kernel_launch(void* const* d_in, const int* in_sizes, int n_in,
                              void* d_out, int out_size, void* d_ws, size_t ws_size,
                              hipStream_t stream)
{
    const float* x  = (const float*)d_in[0];
    const float* w1 = (const float*)d_in[1];
    const float* w2 = (const float*)d_in[2];
    const float* g1 = (const float*)d_in[3];
    const float* b1 = (const float*)d_in[4];
    const float* m1 = (const float*)d_in[5];
    const float* v1 = (const float*)d_in[6];
    const float* g2 = (const float*)d_in[7];
    const float* b2 = (const float*)d_in[8];
    const float* m2 = (const float*)d_in[9];
    const float* v2 = (const float*)d_in[10];

    float* ws    = (float*)d_ws;
    float* s     = ws + OFF_S;
    __hip_bfloat16* sbf = (__hip_bfloat16*)(ws + OFF_SBF);
    float* r     = ws + OFF_R;
    int*   sel   = (int*)(ws + OFF_IDX);
    float* selw  = ws + OFF_W;
    __hip_bfloat16* wt1 = (__hip_bfloat16*)(ws + OFF_WT1);
    __hip_bfloat16* wt2 = (__hip_bfloat16*)(ws + OFF_WT2);
    __hip_bfloat16* h1  = (__hip_bfloat16*)(ws + OFF_H1);
    int*   cand  = (int*)(ws + OFF_CAND);
    float* vals  = ws + OFF_VALS;
    float* out   = (float*)d_out;

    k_trend   <<<dim3(400),         dim3(256), 0, stream>>>(x, out, s, sbf, w1, w2, wt1, wt2, r, vals);
    k_ac_mfma <<<dim3(544),         dim3(256), 0, stream>>>((const short*)sbf, r);
    k_cand    <<<dim3(TB),          dim3(256), 0, stream>>>(r, cand);
    k_rescore <<<dim3(8, 4, TB),    dim3(256), 0, stream>>>(s, cand, vals);
    k_sel     <<<dim3(TB),          dim3(64),  0, stream>>>(vals, cand, sel, selw);
    k_mm1     <<<dim3(32, TK, TB),  dim3(256), 0, stream>>>((const short*)sbf, (const short*)wt1,
                                                            g1, b1, m1, v1, sel, h1);
    k_mm2f    <<<dim3(128, TB),     dim3(256), 0, stream>>>((const short*)h1, (const short*)wt2, s,
                                                            g2, b2, m2, v2, sel, selw, out);
}